// Round 4
// baseline (618.995 us; speedup 1.0000x reference)
//
#include <hip/hip_runtime.h>
#include <hip/hip_cooperative_groups.h>
#include <math.h>

namespace coopg = cooperative_groups;

// Problem constants
#define BB 2
#define CC 128
#define NN 4096            // D*H*W = 16*16*16
#define EE 46              // 16 + 15 + 15 neighbors
#define DS 64              // DSIM = PSIM = GDIM = 64
#define CPAD 16            // dwords per colnorm counter (one 64B line each)
#define NBLK 256           // 1 block/CU — safe under any coop-occupancy model
#define NTHR 256

// ===========================================================================
// Cooperative persistent kernel: 256 blocks x 256 threads, 64 KB LDS.
// Stages separated by grid.sync(); 512-unit stages grid-stride (2 units/blk).
__global__ __launch_bounds__(NTHR) void k_mega(
    const float* __restrict__ x,
    const float* __restrict__ G_w,  const float* __restrict__ G_b,
    const float* __restrict__ th_w, const float* __restrict__ th_b,
    const float* __restrict__ ph_w, const float* __restrict__ ph_b,
    const float* __restrict__ r_w,  const float* __restrict__ r_b,
    const float* __restrict__ gt_w, const float* __restrict__ gt_b,
    const float* __restrict__ gp_w, const float* __restrict__ gp_b,
    float* __restrict__ out,
    int* __restrict__ nbr,
    float* __restrict__ p_theta, float* __restrict__ p_phi,
    float* __restrict__ f_p, float* __restrict__ colnorm_p,
    float* __restrict__ h, float* __restrict__ T, float* __restrict__ P,
    float* __restrict__ Gx, float* __restrict__ f,
    float* __restrict__ colnorm_f)
{
    coopg::grid_group grid = coopg::this_grid();
    const int t = threadIdx.x;
    const int bid = blockIdx.x;
    const int gtid = bid * NTHR + t;

    __shared__ __align__(16) char smem_raw[65536];
    float4* sm4 = (float4*)smem_raw;
    float*  smf = (float*)smem_raw;
    int*    smi = (int*)smem_raw;

    // f-stage for one (b, 16-node tile): dot(T row, gathered P rows) over the
    // neighbor table + per-(b,e) sumsq into cn. 16 groups of 16 lanes:
    // group = node, lane = float4 chunk (coalesced 256 B P-row per group).
    auto f_stage = [&](const float* Ts, const float* Ps, float* fd, float* cn,
                       int b, int tile) {
        float4* ts4 = sm4;                 // [16][17] f4   (dw 0..1087)
        int*    nbs = smi + 1088;          // 736 ints      (dw 1088..1823)
        float*  fvs = smf + 1824;          // 736 floats    (dw 1824..2559)
        {
            int node = t >> 4, kc = t & 15;
            ts4[node * 17 + kc] =
                ((const float4*)Ts)[(size_t)(b * NN + tile * 16 + node) * 16 + kc];
        }
        for (int i2 = t; i2 < 16 * EE; i2 += NTHR)
            nbs[i2] = nbr[tile * 16 * EE + i2];
        __syncthreads();
        const int g = t >> 4, kc = t & 15;
        const int n = tile * 16 + g;
        const float4* P4 = (const float4*)Ps;
        const float4 av = ts4[g * 17 + kc];      // reused for all 46 e
        for (int e = 0; e < EE; ++e) {
            int m = nbs[g * EE + e];
            float4 p = P4[((size_t)b * NN + m) * 16 + kc];
            float v = av.x * p.x + av.y * p.y + av.z * p.z + av.w * p.w;
            v += __shfl_xor(v, 1);
            v += __shfl_xor(v, 2);
            v += __shfl_xor(v, 4);
            v += __shfl_xor(v, 8);
            if (kc == 0) {
                fd[(size_t)(b * NN + n) * EE + e] = v;
                fvs[e * 16 + g] = v;
            }
        }
        __syncthreads();
        // fvs region is disjoint from ts4/nbs, so the next unit's staging
        // cannot clobber it while lanes t<EE finish these reads.
        if (t < EE) {
            float s = 0.f;
#pragma unroll
            for (int q = 0; q < 16; ++q) { float v = fvs[t * 16 + q]; s += v * v; }
            atomicAdd(cn + (b * EE + t) * CPAD, s);
        }
    };

    // ---------------- S0: colnorm_p zero, nbr, geo proj, h transpose --------
    if (gtid < EE * CPAD) colnorm_p[gtid] = 0.f;
    if (gtid < NN) {   // sorted 3-way merge of axis neighbor lists
        int n = gtid;
        int i = n >> 8, j = (n >> 4) & 15, k = n & 15;
        int ia = 0, ib = 0, ic = 0;
        for (int e = 0; e < EE; ++e) {
            int va = (ia < 16) ? ia * 256 + j * 16 + k : 0x7fffffff;
            int jb = ib + (ib >= j ? 1 : 0);
            int vb = (ib < 15) ? i * 256 + jb * 16 + k : 0x7fffffff;
            int kc = ic + (ic >= k ? 1 : 0);
            int vc = (ic < 15) ? i * 256 + j * 16 + kc : 0x7fffffff;
            int v;
            if (va < vb && va < vc)      { v = va; ++ia; }
            else if (vb < vc)            { v = vb; ++ib; }
            else                         { v = vc; ++ic; }
            nbr[n * EE + e] = v;
        }
    }
    for (int idx = gtid; idx < NN * DS; idx += NBLK * NTHR) {
        int n = idx >> 6, s = idx & 63;
        int i = n >> 8, j = (n >> 4) & 15, k = n & 15;
        float p0 = i * (1.f / 15.f) - 0.5f;
        float p1 = j * (1.f / 15.f) - 0.5f;
        float p2 = k * (1.f / 15.f) - 0.5f;
        p_theta[idx] = p0 * gt_w[s * 3] + p1 * gt_w[s * 3 + 1] + p2 * gt_w[s * 3 + 2] + gt_b[s];
        p_phi[idx]   = p0 * gp_w[s * 3] + p1 * gp_w[s * 3 + 1] + p2 * gp_w[s * 3 + 2] + gp_b[s];
    }
    for (int u = bid; u < 512; u += NBLK) {   // h[b][n][c] = x[b][c][n]
        float* xs = smf;                       // [32][65]
        int n0 = (u & 63) * 64, c0 = ((u >> 6) & 3) * 32, b = u >> 8;
        for (int q = t; q < 2048; q += NTHR) {
            int cl = q >> 6, nl = q & 63;
            xs[cl * 65 + nl] = x[(size_t)(b * CC + c0 + cl) * NN + n0 + nl];
        }
        __syncthreads();
        for (int q = t; q < 2048; q += NTHR) {
            int nl = q >> 5, cl = q & 31;
            h[(size_t)(b * NN + n0 + nl) * CC + c0 + cl] = xs[cl * 65 + nl];
        }
        __syncthreads();
    }
    grid.sync();

    // ---------------- S1: geo f_p raw + colnorm_p ---------------------------
    f_stage(p_theta, p_phi, f_p, colnorm_p, 0, bid);   // 256 tiles
    grid.sync();

    // ---------------- rounds ------------------------------------------------
    for (int r = 0; r < 3; ++r) {
        // PROJ: units 0..383 = 64row x 64col tiles (cg 0/1/2 -> T/P/Gx);
        // unit 384 zeroes colnorm_f.
        for (int u = bid; u < 512; u += NBLK) {
            if (u < 384) {
                int row0 = (u & 127) * 64;
                int cgp = u >> 7;
                const float* w    = cgp == 0 ? th_w : cgp == 1 ? ph_w : G_w;
                const float* bias = cgp == 0 ? th_b : cgp == 1 ? ph_b : G_b;
                float* o          = cgp == 0 ? T    : cgp == 1 ? P    : Gx;
                float4* hs4 = sm4;
                float4* ws4 = sm4 + 2048;
                const float4* h4 = (const float4*)h;
                const float4* w4 = (const float4*)w;
                for (int q = t; q < 2048; q += NTHR) {
                    int row = q >> 5, kc = q & 31;
                    hs4[row * 32 + (kc ^ (row & 31))] = h4[(size_t)(row0 + row) * 32 + kc];
                    ws4[row * 32 + (kc ^ (row & 31))] = w4[q];
                }
                __syncthreads();
                const int rt = t >> 4, m = t & 15;
                float acc[4][4] = {};
                for (int kc = 0; kc < 32; ++kc) {
                    float4 a[4], wv[4];
#pragma unroll
                    for (int rr = 0; rr < 4; ++rr) {
                        int rw_ = rt * 4 + rr;
                        a[rr] = hs4[rw_ * 32 + (kc ^ (rw_ & 31))];
                    }
#pragma unroll
                    for (int i = 0; i < 4; ++i) {
                        int c = m + 16 * i;
                        wv[i] = ws4[c * 32 + (kc ^ (c & 31))];
                    }
#pragma unroll
                    for (int rr = 0; rr < 4; ++rr)
#pragma unroll
                        for (int i = 0; i < 4; ++i)
                            acc[rr][i] += a[rr].x * wv[i].x + a[rr].y * wv[i].y
                                        + a[rr].z * wv[i].z + a[rr].w * wv[i].w;
                }
#pragma unroll
                for (int i = 0; i < 4; ++i) {
                    float bv = bias[m + 16 * i];
#pragma unroll
                    for (int rr = 0; rr < 4; ++rr)
                        o[(size_t)(row0 + rt * 4 + rr) * DS + m + 16 * i] = acc[rr][i] + bv;
                }
                __syncthreads();
            } else if (u == 384) {
                for (int i = t; i < BB * EE * CPAD; i += NTHR) colnorm_f[i] = 0.f;
            }
        }
        grid.sync();

        // F: 512 units (b = u>>8, tile = u&255)
        for (int u = bid; u < 512; u += NBLK)
            f_stage(T, P, f, colnorm_f, u >> 8, u & 255);
        grid.sync();

        // ATTN: 512 units of 16 nodes
        {
            float4* rws4 = (float4*)smf;       // 2048 f4, rotation-swizzled
            float*  ys   = smf + 8192;         // [16][68] dwords
            for (int i2 = t; i2 < 2048; i2 += NTHR) {
                int c = i2 >> 4, g4 = i2 & 15;
                rws4[c * 16 + ((g4 + c) & 15)] = ((const float4*)r_w)[i2];
            }
            __syncthreads();
            for (int u = bid; u < 512; u += NBLK) {
                const int tile = u & 255, b = u >> 8, n0 = tile * 16;
                const int wv_ = t >> 6, l = t & 63;
                for (int ii = 0; ii < 4; ++ii) {
                    int nl = wv_ * 4 + ii;
                    int n = n0 + nl;
                    size_t bn = (size_t)b * NN + n;
                    float fvv = -INFINITY; int nb = 0;
                    if (l < EE) {
                        float nf = 1e-6f + sqrtf(colnorm_f[(b * EE + l) * CPAD]);
                        float np = 1e-6f + sqrtf(colnorm_p[l * CPAD]);
                        float fpv = f_p[n * EE + l] / np;
                        fpv = fpv > 0.f ? fpv : 0.f;
                        fvv = f[bn * EE + l] / nf + fpv;
                        nb = nbr[n * EE + l];
                    }
                    float mx = fvv;
                    for (int o = 32; o; o >>= 1) mx = fmaxf(mx, __shfl_down(mx, o));
                    mx = __shfl(mx, 0);
                    float ex = (l < EE) ? expf(fvv - mx) : 0.f;
                    float sm = ex;
                    for (int o = 32; o; o >>= 1) sm += __shfl_down(sm, o);
                    sm = __shfl(sm, 0);
                    float at = ex / sm;
                    const float* Gb = Gx + (size_t)b * NN * DS;
                    float y0 = 0.f, y1 = 0.f;
                    for (int e = 0; e < EE; e += 2) {
                        float a0 = __shfl(at, e);     int m0 = __shfl(nb, e);
                        float a1 = __shfl(at, e + 1); int m1 = __shfl(nb, e + 1);
                        y0 += a0 * Gb[(size_t)m0 * DS + l];
                        y1 += a1 * Gb[(size_t)m1 * DS + l];
                    }
                    ys[nl * 68 + l] = y0 + y1;
                }
                __syncthreads();
                // epilogue: delta[16][128] = y[16][64] @ rw[128][64]^T
                const int r0 = (t >> 5) * 2, cl = t & 31;
                float4* ys4 = (float4*)ys;          // row stride 17 f4
                float acc[2][4] = {{0, 0, 0, 0}, {0, 0, 0, 0}};
                for (int g4 = 0; g4 < 16; ++g4) {
                    float4 ya = ys4[r0 * 17 + g4];
                    float4 yb = ys4[(r0 + 1) * 17 + g4];
#pragma unroll
                    for (int cc = 0; cc < 4; ++cc) {
                        int c = cl + 32 * cc;
                        float4 w = rws4[c * 16 + ((g4 + c) & 15)];
                        acc[0][cc] += ya.x * w.x + ya.y * w.y + ya.z * w.z + ya.w * w.w;
                        acc[1][cc] += yb.x * w.x + yb.y * w.y + yb.z * w.z + yb.w * w.w;
                    }
                }
#pragma unroll
                for (int rr = 0; rr < 2; ++rr) {
                    size_t bn = (size_t)b * NN + n0 + r0 + rr;
#pragma unroll
                    for (int cc = 0; cc < 4; ++cc) {
                        int c = cl + 32 * cc;
                        h[bn * CC + c] += acc[rr][cc] + r_b[c];
                    }
                }
                __syncthreads();
            }
        }
        grid.sync();
    }

    // ---------------- S3: out[b][c][n] = h[b][n][c] -------------------------
    for (int u = bid; u < 512; u += NBLK) {
        float* hs_ = smf;                       // [64][33]
        int n0 = (u & 63) * 64, c0 = ((u >> 6) & 3) * 32, b = u >> 8;
        for (int q = t; q < 2048; q += NTHR) {
            int nl = q >> 5, cl = q & 31;
            hs_[nl * 33 + cl] = h[(size_t)(b * NN + n0 + nl) * CC + c0 + cl];
        }
        __syncthreads();
        for (int q = t; q < 2048; q += NTHR) {
            int cl = q >> 6, nl = q & 63;
            out[(size_t)(b * CC + c0 + cl) * NN + n0 + nl] = hs_[nl * 33 + cl];
        }
        __syncthreads();
    }
}

// ===========================================================================
// Fallback path: round-2 verified multi-kernel pipeline (passed @ 256 µs).
// ===========================================================================
__global__ void k_nbr(int* __restrict__ nbr, float* __restrict__ colnorm_p) {
    int n = blockIdx.x * blockDim.x + threadIdx.x;
    if (blockIdx.x == 0)
        for (int i = threadIdx.x; i < EE * CPAD; i += 256) colnorm_p[i] = 0.f;
    if (n >= NN) return;
    int i = n >> 8, j = (n >> 4) & 15, k = n & 15;
    int ia = 0, ib = 0, ic = 0;
    for (int e = 0; e < EE; ++e) {
        int va = (ia < 16) ? ia * 256 + j * 16 + k : 0x7fffffff;
        int jb = ib + (ib >= j ? 1 : 0);
        int vb = (ib < 15) ? i * 256 + jb * 16 + k : 0x7fffffff;
        int kc = ic + (ic >= k ? 1 : 0);
        int vc = (ic < 15) ? i * 256 + j * 16 + kc : 0x7fffffff;
        int v;
        if (va < vb && va < vc)      { v = va; ++ia; }
        else if (vb < vc)            { v = vb; ++ib; }
        else                         { v = vc; ++ic; }
        nbr[n * EE + e] = v;
    }
}

__global__ void k_geo(const float* __restrict__ gtw, const float* __restrict__ gtb,
                      const float* __restrict__ gpw, const float* __restrict__ gpb,
                      float* __restrict__ p_theta, float* __restrict__ p_phi) {
    int idx = blockIdx.x * blockDim.x + threadIdx.x;
    if (idx >= NN * DS) return;
    int n = idx >> 6, s = idx & 63;
    int i = n >> 8, j = (n >> 4) & 15, k = n & 15;
    float p0 = i * (1.f / 15.f) - 0.5f;
    float p1 = j * (1.f / 15.f) - 0.5f;
    float p2 = k * (1.f / 15.f) - 0.5f;
    p_theta[idx] = p0 * gtw[s * 3] + p1 * gtw[s * 3 + 1] + p2 * gtw[s * 3 + 2] + gtb[s];
    p_phi[idx]   = p0 * gpw[s * 3] + p1 * gpw[s * 3 + 1] + p2 * gpw[s * 3 + 2] + gpb[s];
}

__global__ __launch_bounds__(256) void k_f(const int* __restrict__ nbr,
        const float* __restrict__ T, const float* __restrict__ P,
        float* __restrict__ f, float* __restrict__ colnorm) {
    __shared__ float4 ts4[16 * 17];
    __shared__ int nbr_s[16 * EE];
    const int t = threadIdx.x;
    const int b = blockIdx.y;
    const int tile = blockIdx.x;
    {
        int node = t >> 4, kc = t & 15;
        ts4[node * 17 + kc] = ((const float4*)T)[(size_t)(b * NN + tile * 16 + node) * 16 + kc];
    }
    for (int i = t; i < 16 * EE; i += 256) nbr_s[i] = nbr[tile * 16 * EE + i];
    __syncthreads();
    const int li = t >> 4, nl = t & 15;
    const int n = tile * 16 + nl;
    const float4* P4 = (const float4*)P;
    float sq[3] = {0.f, 0.f, 0.f};
#pragma unroll
    for (int s = 0; s < 3; ++s) {
        int e = li + 16 * s;
        if (e < EE) {
            int mm = nbr_s[nl * EE + e];
            const float4* pr = P4 + (size_t)(b * NN + mm) * 16;
            float acc = 0.f;
#pragma unroll
            for (int kc = 0; kc < 16; ++kc) {
                float4 a = ts4[nl * 17 + kc];
                float4 p = pr[kc];
                acc += a.x * p.x + a.y * p.y + a.z * p.z + a.w * p.w;
            }
            f[(size_t)(b * NN + n) * EE + e] = acc;
            sq[s] = acc * acc;
        }
    }
#pragma unroll
    for (int s = 0; s < 3; ++s) {
        float v = sq[s];
        v += __shfl_down(v, 8);
        v += __shfl_down(v, 4);
        v += __shfl_down(v, 2);
        v += __shfl_down(v, 1);
        if (nl == 0) {
            int e = li + 16 * s;
            if (e < EE) atomicAdd(colnorm + (b * EE + e) * CPAD, v);
        }
    }
}

__global__ void k_fpfin(float* __restrict__ fp, const float* __restrict__ colnorm_p) {
    int t = blockIdx.x * 256 + threadIdx.x;
    if (t >= NN * EE) return;
    int e = t % EE;
    float nrm = 1e-6f + sqrtf(colnorm_p[e * CPAD]);
    float v = fp[t] / nrm;
    fp[t] = v > 0.f ? v : 0.f;
}

__global__ __launch_bounds__(256) void k_hinit(const float* __restrict__ x,
                                               float* __restrict__ h) {
    __shared__ float xs[32][65];
    const int t = threadIdx.x;
    const int n0 = blockIdx.x * 64, c0 = blockIdx.y * 32, b = blockIdx.z;
    for (int q = t; q < 2048; q += 256) {
        int cl = q >> 6, nl = q & 63;
        xs[cl][nl] = x[(size_t)(b * CC + c0 + cl) * NN + n0 + nl];
    }
    __syncthreads();
    for (int q = t; q < 2048; q += 256) {
        int nl = q >> 5, cl = q & 31;
        h[(size_t)(b * NN + n0 + nl) * CC + c0 + cl] = xs[cl][nl];
    }
}

__global__ __launch_bounds__(256) void k_proj(const float* __restrict__ h,
        const float* __restrict__ thw, const float* __restrict__ thb,
        const float* __restrict__ phw, const float* __restrict__ phb,
        const float* __restrict__ gw,  const float* __restrict__ gb,
        float* __restrict__ T, float* __restrict__ P, float* __restrict__ G,
        float* __restrict__ colnorm_f) {
    __shared__ float4 smem[4096];
    float4* hs4 = smem;
    float4* ws4 = smem + 2048;
    const int t = threadIdx.x;
    const int cg = blockIdx.y;
    const int row0 = blockIdx.x * 64;
    if (blockIdx.x == 0 && cg == 0)
        for (int i = t; i < BB * EE * CPAD; i += 256) colnorm_f[i] = 0.f;
    const float* w    = (cg == 0) ? thw : (cg == 1) ? phw : gw;
    const float* bias = (cg == 0) ? thb : (cg == 1) ? phb : gb;
    float* out        = (cg == 0) ? T   : (cg == 1) ? P   : G;
    const float4* h4 = (const float4*)h;
    const float4* w4 = (const float4*)w;
    for (int q = t; q < 2048; q += 256) {
        int row = q >> 5, kc = q & 31;
        hs4[row * 32 + (kc ^ (row & 31))] = h4[(size_t)(row0 + row) * 32 + kc];
        ws4[row * 32 + (kc ^ (row & 31))] = w4[q];
    }
    __syncthreads();
    const int rt = t >> 4, m = t & 15;
    float acc[4][4] = {};
    for (int kc = 0; kc < 32; ++kc) {
        float4 a[4], wv[4];
#pragma unroll
        for (int rr = 0; rr < 4; ++rr) {
            int rw_ = rt * 4 + rr;
            a[rr] = hs4[rw_ * 32 + (kc ^ (rw_ & 31))];
        }
#pragma unroll
        for (int i = 0; i < 4; ++i) {
            int c = m + 16 * i;
            wv[i] = ws4[c * 32 + (kc ^ (c & 31))];
        }
#pragma unroll
        for (int rr = 0; rr < 4; ++rr)
#pragma unroll
            for (int i = 0; i < 4; ++i)
                acc[rr][i] += a[rr].x * wv[i].x + a[rr].y * wv[i].y
                            + a[rr].z * wv[i].z + a[rr].w * wv[i].w;
    }
#pragma unroll
    for (int i = 0; i < 4; ++i) {
        float bv = bias[m + 16 * i];
#pragma unroll
        for (int rr = 0; rr < 4; ++rr)
            out[(size_t)(row0 + rt * 4 + rr) * DS + m + 16 * i] = acc[rr][i] + bv;
    }
}

__global__ __launch_bounds__(64) void k_attn(const float* __restrict__ f,
        const float* __restrict__ colnorm, const float* __restrict__ f_p,
        const int* __restrict__ nbr, const float* __restrict__ Gx,
        const float* __restrict__ rw, const float* __restrict__ rb,
        float* __restrict__ h) {
    const int bn = blockIdx.x, b = bn >> 12, n = bn & (NN - 1), l = threadIdx.x;
    __shared__ float attn_s[EE];
    __shared__ int   nb_s[EE];
    __shared__ __align__(16) float y_s[DS];

    float fv = -INFINITY;
    if (l < EE) {
        float nrm = 1e-6f + sqrtf(colnorm[(b * EE + l) * CPAD]);
        fv = f[(size_t)bn * EE + l] / nrm + f_p[n * EE + l];
        nb_s[l] = nbr[n * EE + l];
    }
    float mx = fv;
    for (int o = 32; o; o >>= 1) mx = fmaxf(mx, __shfl_down(mx, o));
    mx = __shfl(mx, 0);
    float ex = (l < EE) ? expf(fv - mx) : 0.f;
    float sm = ex;
    for (int o = 32; o; o >>= 1) sm += __shfl_down(sm, o);
    sm = __shfl(sm, 0);
    if (l < EE) attn_s[l] = ex / sm;
    __syncthreads();

    float y0 = 0.f, y1 = 0.f;
#pragma unroll
    for (int e = 0; e < EE; e += 2) {
        y0 += attn_s[e]     * Gx[(size_t)(b * NN + nb_s[e])     * DS + l];
        y1 += attn_s[e + 1] * Gx[(size_t)(b * NN + nb_s[e + 1]) * DS + l];
    }
    y_s[l] = y0 + y1;
    __syncthreads();

    const float4* rw4 = (const float4*)rw;
    const float4* ys4 = (const float4*)y_s;
    float acc0 = rb[l], acc1 = rb[l + 64];
#pragma unroll
    for (int g = 0; g < 16; ++g) {
        float4 yv = ys4[g];
        float4 w0 = rw4[l * 16 + g];
        float4 w1 = rw4[(l + 64) * 16 + g];
        acc0 += yv.x * w0.x + yv.y * w0.y + yv.z * w0.z + yv.w * w0.w;
        acc1 += yv.x * w1.x + yv.y * w1.y + yv.z * w1.z + yv.w * w1.w;
    }
    h[(size_t)bn * CC + l]      += acc0;
    h[(size_t)bn * CC + l + 64] += acc1;
}

__global__ __launch_bounds__(256) void k_out(const float* __restrict__ h,
                                             float* __restrict__ out) {
    __shared__ float hs_[64][33];
    const int t = threadIdx.x;
    const int n0 = blockIdx.x * 64, c0 = blockIdx.y * 32, b = blockIdx.z;
    for (int q = t; q < 2048; q += 256) {
        int nl = q >> 5, cl = q & 31;
        hs_[nl][cl] = h[(size_t)(b * NN + n0 + nl) * CC + c0 + cl];
    }
    __syncthreads();
    for (int q = t; q < 2048; q += 256) {
        int cl = q >> 6, nl = q & 63;
        out[(size_t)(b * CC + c0 + cl) * NN + n0 + nl] = hs_[nl][cl];
    }
}

// ===========================================================================
extern "C" void kernel_launch(void* const* d_in, const int* in_sizes, int n_in,
                              void* d_out, int out_size, void* d_ws, size_t ws_size,
                              hipStream_t stream) {
    const float* x    = (const float*)d_in[0];
    const float* G_w  = (const float*)d_in[1];
    const float* G_b  = (const float*)d_in[2];
    const float* th_w = (const float*)d_in[3];
    const float* th_b = (const float*)d_in[4];
    const float* ph_w = (const float*)d_in[5];
    const float* ph_b = (const float*)d_in[6];
    const float* r_w  = (const float*)d_in[7];
    const float* r_b  = (const float*)d_in[8];
    const float* gt_w = (const float*)d_in[9];
    const float* gt_b = (const float*)d_in[10];
    const float* gp_w = (const float*)d_in[11];
    const float* gp_b = (const float*)d_in[12];
    float* out = (float*)d_out;

    // Workspace layout (byte offsets, 256-aligned)
    char* ws = (char*)d_ws;
    size_t off = 0;
    auto alloc = [&](size_t bytes) {
        char* p = ws + off;
        off = (off + bytes + 255) & ~size_t(255);
        return p;
    };
    int*   nbr       = (int*)  alloc((size_t)NN * EE * sizeof(int));
    float* p_theta   = (float*)alloc((size_t)NN * DS * sizeof(float));
    float* p_phi     = (float*)alloc((size_t)NN * DS * sizeof(float));
    float* f_p       = (float*)alloc((size_t)NN * EE * sizeof(float));
    float* colnorm_p = (float*)alloc((size_t)EE * CPAD * sizeof(float));
    float* h         = (float*)alloc((size_t)BB * NN * CC * sizeof(float));
    float* T         = (float*)alloc((size_t)BB * NN * DS * sizeof(float));
    float* P         = (float*)alloc((size_t)BB * NN * DS * sizeof(float));
    float* Gx        = (float*)alloc((size_t)BB * NN * DS * sizeof(float));
    float* f         = (float*)alloc((size_t)BB * NN * EE * sizeof(float));
    float* colnorm_f = (float*)alloc((size_t)BB * EE * CPAD * sizeof(float));
    (void)ws_size; (void)in_sizes; (void)n_in; (void)out_size;

    void* args[] = {
        (void*)&x,
        (void*)&G_w,  (void*)&G_b,
        (void*)&th_w, (void*)&th_b,
        (void*)&ph_w, (void*)&ph_b,
        (void*)&r_w,  (void*)&r_b,
        (void*)&gt_w, (void*)&gt_b,
        (void*)&gp_w, (void*)&gp_b,
        (void*)&out,
        (void*)&nbr,
        (void*)&p_theta, (void*)&p_phi,
        (void*)&f_p, (void*)&colnorm_p,
        (void*)&h, (void*)&T, (void*)&P,
        (void*)&Gx, (void*)&f, (void*)&colnorm_f,
    };
    hipError_t err = hipLaunchCooperativeKernel((const void*)k_mega, dim3(NBLK),
                                                dim3(NTHR), args, 0, stream);
    if (err == hipSuccess) return;

    // Fallback: verified multi-kernel pipeline
    k_nbr<<<NN / 256, 256, 0, stream>>>(nbr, colnorm_p);
    k_geo<<<(NN * DS) / 256, 256, 0, stream>>>(gt_w, gt_b, gp_w, gp_b, p_theta, p_phi);
    k_f<<<dim3(NN / 16, 1), 256, 0, stream>>>(nbr, p_theta, p_phi, f_p, colnorm_p);
    k_fpfin<<<(NN * EE) / 256, 256, 0, stream>>>(f_p, colnorm_p);
    k_hinit<<<dim3(NN / 64, CC / 32, BB), 256, 0, stream>>>(x, h);
    for (int r = 0; r < 3; ++r) {
        k_proj<<<dim3(BB * NN / 64, 3), 256, 0, stream>>>(h, th_w, th_b, ph_w, ph_b,
                                                          G_w, G_b, T, P, Gx, colnorm_f);
        k_f<<<dim3(NN / 16, BB), 256, 0, stream>>>(nbr, T, P, f, colnorm_f);
        k_attn<<<BB * NN, 64, 0, stream>>>(f, colnorm_f, f_p, nbr, Gx, r_w, r_b, h);
    }
    k_out<<<dim3(NN / 64, CC / 32, BB), 256, 0, stream>>>(h, out);
}

// Round 5
// 440.618 us; speedup vs baseline: 1.4048x; 1.4048x over previous
//
#include <hip/hip_runtime.h>
#include <math.h>

// Problem constants
#define BB 2
#define CC 128
#define NN 4096            // D*H*W = 16*16*16
#define EE 46              // 16 + 15 + 15 neighbors
#define DS 64              // DSIM = PSIM = GDIM = 64
#define CPAD 16            // dwords per colnorm counter (one 64B line each)

// ===========================================================================
// Setup: zero counters/colnorms, neighbor table, geo projections, h transpose.
// grid 512 x 256.
__global__ __launch_bounds__(256) void k_setup(
    const float* __restrict__ x,
    const float* __restrict__ gt_w, const float* __restrict__ gt_b,
    const float* __restrict__ gp_w, const float* __restrict__ gp_b,
    int* __restrict__ nbr, float* __restrict__ p_theta, float* __restrict__ p_phi,
    float* __restrict__ colnorm_p, float* __restrict__ colnorm_f,
    int* __restrict__ ctr, float* __restrict__ h)
{
    __shared__ float xs[32 * 65];
    const int t = threadIdx.x, bid = blockIdx.x;
    const int gtid = bid * 256 + t;

    if (gtid < EE * CPAD) colnorm_p[gtid] = 0.f;
    if (gtid < 3 * BB * EE * CPAD) colnorm_f[gtid] = 0.f;
    if (gtid < 4) ctr[gtid] = 0;

    if (gtid < NN) {   // sorted 3-way merge of axis neighbor lists
        int n = gtid;
        int i = n >> 8, j = (n >> 4) & 15, k = n & 15;
        int ia = 0, ib = 0, ic = 0;
        for (int e = 0; e < EE; ++e) {
            int va = (ia < 16) ? ia * 256 + j * 16 + k : 0x7fffffff;
            int jb = ib + (ib >= j ? 1 : 0);
            int vb = (ib < 15) ? i * 256 + jb * 16 + k : 0x7fffffff;
            int kc = ic + (ic >= k ? 1 : 0);
            int vc = (ic < 15) ? i * 256 + j * 16 + kc : 0x7fffffff;
            int v;
            if (va < vb && va < vc)      { v = va; ++ia; }
            else if (vb < vc)            { v = vb; ++ib; }
            else                         { v = vc; ++ic; }
            nbr[n * EE + e] = v;
        }
    }
    for (int idx = gtid; idx < NN * DS; idx += 512 * 256) {
        int n = idx >> 6, s = idx & 63;
        int i = n >> 8, j = (n >> 4) & 15, k = n & 15;
        float p0 = i * (1.f / 15.f) - 0.5f;
        float p1 = j * (1.f / 15.f) - 0.5f;
        float p2 = k * (1.f / 15.f) - 0.5f;
        p_theta[idx] = p0 * gt_w[s * 3] + p1 * gt_w[s * 3 + 1] + p2 * gt_w[s * 3 + 2] + gt_b[s];
        p_phi[idx]   = p0 * gp_w[s * 3] + p1 * gp_w[s * 3 + 1] + p2 * gp_w[s * 3 + 2] + gp_b[s];
    }
    {   // h[b][n][c] = x[b][c][n], one 64n x 32c tile per block
        int n0 = (bid & 63) * 64, c0 = ((bid >> 6) & 3) * 32, b = bid >> 8;
        for (int q = t; q < 2048; q += 256) {
            int cl = q >> 6, nl = q & 63;
            xs[cl * 65 + nl] = x[(size_t)(b * CC + c0 + cl) * NN + n0 + nl];
        }
        __syncthreads();
        for (int q = t; q < 2048; q += 256) {
            int nl = q >> 5, cl = q & 31;
            h[(size_t)(b * NN + n0 + nl) * CC + c0 + cl] = xs[cl * 65 + nl];
        }
    }
}

// ===========================================================================
// proj: [8192x128]x[128x192]^T GEMM (blocks 0..383, 64x64 tiles, XOR-swizzled
// LDS, 4x4 register blocking). Blocks >=384 (round-0 launch only) compute the
// one-time geo f_p raw dots + colnorm_p atomics.
__global__ __launch_bounds__(256) void k_proj(
    const float* __restrict__ h,
    const float* __restrict__ th_w, const float* __restrict__ th_b,
    const float* __restrict__ ph_w, const float* __restrict__ ph_b,
    const float* __restrict__ G_w,  const float* __restrict__ G_b,
    float* __restrict__ T, float* __restrict__ P, float* __restrict__ Gx,
    const int* __restrict__ nbr,
    const float* __restrict__ p_theta, const float* __restrict__ p_phi,
    float* __restrict__ f_p, float* __restrict__ colnorm_p)
{
    __shared__ __align__(16) float smf[16384];   // 64 KB
    const int t = threadIdx.x;
    if (blockIdx.x < 384) {
        int row0 = (blockIdx.x & 127) * 64;
        int cgp = blockIdx.x >> 7;
        const float* w    = cgp == 0 ? th_w : cgp == 1 ? ph_w : G_w;
        const float* bias = cgp == 0 ? th_b : cgp == 1 ? ph_b : G_b;
        float* o          = cgp == 0 ? T    : cgp == 1 ? P    : Gx;
        float4* hs4 = (float4*)smf;
        float4* ws4 = (float4*)smf + 2048;
        const float4* h4 = (const float4*)h;
        const float4* w4 = (const float4*)w;
        for (int q = t; q < 2048; q += 256) {
            int row = q >> 5, kc = q & 31;
            hs4[row * 32 + (kc ^ (row & 31))] = h4[(size_t)(row0 + row) * 32 + kc];
            ws4[row * 32 + (kc ^ (row & 31))] = w4[q];
        }
        __syncthreads();
        const int rt = t >> 4, m = t & 15;
        float acc[4][4] = {};
        for (int kc = 0; kc < 32; ++kc) {
            float4 a[4], wv[4];
#pragma unroll
            for (int rr = 0; rr < 4; ++rr) {
                int rw_ = rt * 4 + rr;
                a[rr] = hs4[rw_ * 32 + (kc ^ (rw_ & 31))];
            }
#pragma unroll
            for (int i = 0; i < 4; ++i) {
                int c = m + 16 * i;
                wv[i] = ws4[c * 32 + (kc ^ (c & 31))];
            }
#pragma unroll
            for (int rr = 0; rr < 4; ++rr)
#pragma unroll
                for (int i = 0; i < 4; ++i)
                    acc[rr][i] += a[rr].x * wv[i].x + a[rr].y * wv[i].y
                                + a[rr].z * wv[i].z + a[rr].w * wv[i].w;
        }
#pragma unroll
        for (int i = 0; i < 4; ++i) {
            float bv = bias[m + 16 * i];
#pragma unroll
            for (int rr = 0; rr < 4; ++rr)
                o[(size_t)(row0 + rt * 4 + rr) * DS + m + 16 * i] = acc[rr][i] + bv;
        }
    } else {
        // geo f_p: tile = blockIdx.x - 384 (b implicit 0, batch-identical)
        const int tile = blockIdx.x - 384;
        float4* ts4 = (float4*)smf;          // [16][17] f4  (dw 0..1087)
        int*    nbs = (int*)(smf + 1088);    // 736 ints
        float*  fvs = smf + 1824;            // 736 floats
        {
            int node = t >> 4, kc = t & 15;
            ts4[node * 17 + kc] =
                ((const float4*)p_theta)[(size_t)(tile * 16 + node) * 16 + kc];
        }
        for (int i2 = t; i2 < 16 * EE; i2 += 256) nbs[i2] = nbr[tile * 16 * EE + i2];
        __syncthreads();
        const int g = t >> 4, kc = t & 15;
        const float4 av = ts4[g * 17 + kc];
        const float4* P4 = (const float4*)p_phi;
        for (int e = 0; e < EE; ++e) {
            int m = nbs[g * EE + e];
            float4 p = P4[(size_t)m * 16 + kc];
            float v = av.x * p.x + av.y * p.y + av.z * p.z + av.w * p.w;
            v += __shfl_xor(v, 1);
            v += __shfl_xor(v, 2);
            v += __shfl_xor(v, 4);
            v += __shfl_xor(v, 8);
            if (kc == 0) {
                f_p[(size_t)(tile * 16 + g) * EE + e] = v;
                fvs[e * 16 + g] = v;
            }
        }
        __syncthreads();
        if (t < EE) {
            float s = 0.f;
#pragma unroll
            for (int q = 0; q < 16; ++q) { float v = fvs[t * 16 + q]; s += v * v; }
            atomicAdd(colnorm_p + t * CPAD, s);
        }
    }
}

// ===========================================================================
// Fused f + attn: per (b, 16-node tile) block. Phase 1 computes f into LDS +
// atomicAdd sumsq partials; lightweight device-scope atomic barrier (no L2
// flush needed — the only cross-block data is the atomics themselves); phase 2
// softmax + gather + r_w epilogue + residual. 512 blocks; launch_bounds(256,2)
// + 43KB LDS guarantee 2 blocks/CU co-residency (grid == capacity).
__global__ __launch_bounds__(256, 2) void k_fattn(
    const int* __restrict__ nbr,
    const float* __restrict__ T, const float* __restrict__ P,
    const float* __restrict__ Gx, const float* __restrict__ f_p,
    const float* __restrict__ colnorm_p, float* __restrict__ colnorm_f,
    int* __restrict__ ctr,
    const float* __restrict__ r_w, const float* __restrict__ r_b,
    float* __restrict__ h)
{
    __shared__ __align__(16) float smf[10752];   // 43008 B
    float4* rws4 = (float4*)smf;                 // dw 0..8191 (rotation-swz)
    float4* ts4  = (float4*)(smf + 8192);        // [16][17] f4, dw 8192..9279
    float*  ys   = smf + 8192;                   // reuse as [16][68]
    int*    nbs  = (int*)(smf + 9280);           // 736 ints
    float*  fvs  = smf + 10016;                  // 736 floats

    const int t = threadIdx.x;
    const int u = blockIdx.x;                    // 0..511
    const int b = u >> 8, tile = u & 255, n0 = tile * 16;

    // ---- stage T rows, neighbor tile, r_w -----------------------------------
    {
        int node = t >> 4, kc = t & 15;
        ts4[node * 17 + kc] =
            ((const float4*)T)[(size_t)(b * NN + n0 + node) * 16 + kc];
    }
    for (int i2 = t; i2 < 16 * EE; i2 += 256) nbs[i2] = nbr[n0 * EE + i2];
    for (int i2 = t; i2 < 2048; i2 += 256) {
        int c = i2 >> 4, g4 = i2 & 15;
        rws4[c * 16 + ((g4 + c) & 15)] = ((const float4*)r_w)[i2];
    }
    __syncthreads();

    // ---- phase 1: f dots (kept in LDS, never written to global) -------------
    const int g = t >> 4, kc = t & 15;
    const float4 av = ts4[g * 17 + kc];
    const float4* P4 = (const float4*)P;
    for (int e = 0; e < EE; ++e) {
        int m = nbs[g * EE + e];
        float4 p = P4[((size_t)b * NN + m) * 16 + kc];
        float v = av.x * p.x + av.y * p.y + av.z * p.z + av.w * p.w;
        v += __shfl_xor(v, 1);
        v += __shfl_xor(v, 2);
        v += __shfl_xor(v, 4);
        v += __shfl_xor(v, 8);
        if (kc == 0) fvs[e * 16 + g] = v;
    }
    __syncthreads();
    if (t < EE) {
        float s = 0.f;
#pragma unroll
        for (int q = 0; q < 16; ++q) { float v = fvs[t * 16 + q]; s += v * v; }
        atomicAdd(colnorm_f + (b * EE + t) * CPAD, s);
    }
    __threadfence();
    __syncthreads();

    // ---- lightweight global barrier (atomics only — no cache flush) ---------
    if (t == 0) {
        __hip_atomic_fetch_add(ctr, 1, __ATOMIC_RELEASE, __HIP_MEMORY_SCOPE_AGENT);
        while (__hip_atomic_load(ctr, __ATOMIC_ACQUIRE, __HIP_MEMORY_SCOPE_AGENT)
               < BB * 256)
            __builtin_amdgcn_s_sleep(2);
    }
    __syncthreads();

    // ---- phase 2: softmax + gather + epilogue -------------------------------
    const int wv = t >> 6, l = t & 63;
    float nf_inv = 0.f, np_inv = 0.f;
    if (l < EE) {
        float cf = __hip_atomic_load(colnorm_f + (b * EE + l) * CPAD,
                                     __ATOMIC_RELAXED, __HIP_MEMORY_SCOPE_AGENT);
        float cp = colnorm_p[l * CPAD];
        nf_inv = 1.f / (1e-6f + sqrtf(cf));
        np_inv = 1.f / (1e-6f + sqrtf(cp));
    }
    const float* Gb = Gx + (size_t)b * NN * DS;
    for (int ii = 0; ii < 4; ++ii) {
        int nl = wv * 4 + ii;
        int n = n0 + nl;
        float fvv = -INFINITY; int nb = 0;
        if (l < EE) {
            float fpv = f_p[(size_t)n * EE + l] * np_inv;
            fpv = fpv > 0.f ? fpv : 0.f;
            fvv = fvs[l * 16 + nl] * nf_inv + fpv;
            nb = nbs[nl * EE + l];
        }
        float mx = fvv;
        for (int o = 32; o; o >>= 1) mx = fmaxf(mx, __shfl_down(mx, o));
        mx = __shfl(mx, 0);
        float ex = (l < EE) ? expf(fvv - mx) : 0.f;
        float sm = ex;
        for (int o = 32; o; o >>= 1) sm += __shfl_down(sm, o);
        sm = __shfl(sm, 0);
        float at = ex / sm;
        float y0 = 0.f, y1 = 0.f;
        for (int e = 0; e < EE; e += 2) {
            float a0 = __shfl(at, e);     int m0 = __shfl(nb, e);
            float a1 = __shfl(at, e + 1); int m1 = __shfl(nb, e + 1);
            y0 += a0 * Gb[(size_t)m0 * DS + l];
            y1 += a1 * Gb[(size_t)m1 * DS + l];
        }
        ys[nl * 68 + l] = y0 + y1;
    }
    __syncthreads();

    // epilogue: delta[16][128] = y[16][64] @ rw[128][64]^T, residual into h
    const int r0 = (t >> 5) * 2, cl = t & 31;
    float4* ys4 = (float4*)ys;                   // row stride 17 f4
    float acc[2][4] = {{0, 0, 0, 0}, {0, 0, 0, 0}};
    for (int g4 = 0; g4 < 16; ++g4) {
        float4 ya = ys4[r0 * 17 + g4];
        float4 yb = ys4[(r0 + 1) * 17 + g4];
#pragma unroll
        for (int cc = 0; cc < 4; ++cc) {
            int c = cl + 32 * cc;
            float4 w = rws4[c * 16 + ((g4 + c) & 15)];
            acc[0][cc] += ya.x * w.x + ya.y * w.y + ya.z * w.z + ya.w * w.w;
            acc[1][cc] += yb.x * w.x + yb.y * w.y + yb.z * w.z + yb.w * w.w;
        }
    }
#pragma unroll
    for (int rr = 0; rr < 2; ++rr) {
        size_t bn = (size_t)b * NN + n0 + r0 + rr;
#pragma unroll
        for (int cc = 0; cc < 4; ++cc) {
            int c = cl + 32 * cc;
            h[bn * CC + c] += acc[rr][cc] + r_b[c];
        }
    }
}

// ===========================================================================
// out[b][c][n] = h[b][n][c]
__global__ __launch_bounds__(256) void k_out(const float* __restrict__ h,
                                             float* __restrict__ out) {
    __shared__ float hs_[64][33];
    const int t = threadIdx.x;
    const int n0 = blockIdx.x * 64, c0 = blockIdx.y * 32, b = blockIdx.z;
    for (int q = t; q < 2048; q += 256) {
        int nl = q >> 5, cl = q & 31;
        hs_[nl][cl] = h[(size_t)(b * NN + n0 + nl) * CC + c0 + cl];
    }
    __syncthreads();
    for (int q = t; q < 2048; q += 256) {
        int cl = q >> 6, nl = q & 63;
        out[(size_t)(b * CC + c0 + cl) * NN + n0 + nl] = hs_[nl][cl];
    }
}

// ===========================================================================
extern "C" void kernel_launch(void* const* d_in, const int* in_sizes, int n_in,
                              void* d_out, int out_size, void* d_ws, size_t ws_size,
                              hipStream_t stream) {
    const float* x    = (const float*)d_in[0];
    const float* G_w  = (const float*)d_in[1];
    const float* G_b  = (const float*)d_in[2];
    const float* th_w = (const float*)d_in[3];
    const float* th_b = (const float*)d_in[4];
    const float* ph_w = (const float*)d_in[5];
    const float* ph_b = (const float*)d_in[6];
    const float* r_w  = (const float*)d_in[7];
    const float* r_b  = (const float*)d_in[8];
    const float* gt_w = (const float*)d_in[9];
    const float* gt_b = (const float*)d_in[10];
    const float* gp_w = (const float*)d_in[11];
    const float* gp_b = (const float*)d_in[12];
    float* out = (float*)d_out;

    // Workspace layout (byte offsets, 256-aligned)
    char* ws = (char*)d_ws;
    size_t off = 0;
    auto alloc = [&](size_t bytes) {
        char* p = ws + off;
        off = (off + bytes + 255) & ~size_t(255);
        return p;
    };
    int*   nbr       = (int*)  alloc((size_t)NN * EE * sizeof(int));
    float* p_theta   = (float*)alloc((size_t)NN * DS * sizeof(float));
    float* p_phi     = (float*)alloc((size_t)NN * DS * sizeof(float));
    float* f_p       = (float*)alloc((size_t)NN * EE * sizeof(float));
    float* colnorm_p = (float*)alloc((size_t)EE * CPAD * sizeof(float));
    float* colnorm_f = (float*)alloc((size_t)3 * BB * EE * CPAD * sizeof(float));
    int*   ctr       = (int*)  alloc(4 * sizeof(int));
    float* h         = (float*)alloc((size_t)BB * NN * CC * sizeof(float));
    float* T         = (float*)alloc((size_t)BB * NN * DS * sizeof(float));
    float* P         = (float*)alloc((size_t)BB * NN * DS * sizeof(float));
    float* Gx        = (float*)alloc((size_t)BB * NN * DS * sizeof(float));
    (void)ws_size; (void)in_sizes; (void)n_in; (void)out_size;

    k_setup<<<512, 256, 0, stream>>>(x, gt_w, gt_b, gp_w, gp_b, nbr,
                                     p_theta, p_phi, colnorm_p, colnorm_f, ctr, h);
    for (int r = 0; r < 3; ++r) {
        // round 0 carries the one-time geo f_p blocks (384..639)
        int nblk = (r == 0) ? 640 : 384;
        k_proj<<<nblk, 256, 0, stream>>>(h, th_w, th_b, ph_w, ph_b, G_w, G_b,
                                         T, P, Gx, nbr, p_theta, p_phi,
                                         f_p, colnorm_p);
        k_fattn<<<512, 256, 0, stream>>>(nbr, T, P, Gx, f_p, colnorm_p,
                                         colnorm_f + (size_t)r * BB * EE * CPAD,
                                         ctr + r, r_w, r_b, h);
    }
    k_out<<<dim3(64, 4, 2), 256, 0, stream>>>(h, out);
}

// Round 6
// 298.861 us; speedup vs baseline: 2.0712x; 1.4743x over previous
//
#include <hip/hip_runtime.h>
#include <math.h>

// Problem constants
#define BB 2
#define CC 128
#define NN 4096            // D*H*W = 16*16*16
#define EE 46              // 16 + 15 + 15 neighbors
#define DS 64              // DSIM = PSIM = GDIM = 64
#define CPAD 16            // dwords per colnorm counter (one 64B line each)

// ===========================================================================
// Setup: zero counters/colnorms, neighbor table, geo projections, h transpose.
// grid 512 x 256.
__global__ __launch_bounds__(256) void k_setup(
    const float* __restrict__ x,
    const float* __restrict__ gt_w, const float* __restrict__ gt_b,
    const float* __restrict__ gp_w, const float* __restrict__ gp_b,
    int* __restrict__ nbr, float* __restrict__ p_theta, float* __restrict__ p_phi,
    float* __restrict__ colnorm_p, float* __restrict__ colnorm_f,
    int* __restrict__ ctr, float* __restrict__ h)
{
    __shared__ float xs[32 * 65];
    const int t = threadIdx.x, bid = blockIdx.x;
    const int gtid = bid * 256 + t;

    if (gtid < EE * CPAD) colnorm_p[gtid] = 0.f;
    if (gtid < 3 * BB * EE * CPAD) colnorm_f[gtid] = 0.f;
    if (gtid < 4) ctr[gtid] = 0;

    if (gtid < NN) {   // sorted 3-way merge of axis neighbor lists
        int n = gtid;
        int i = n >> 8, j = (n >> 4) & 15, k = n & 15;
        int ia = 0, ib = 0, ic = 0;
        for (int e = 0; e < EE; ++e) {
            int va = (ia < 16) ? ia * 256 + j * 16 + k : 0x7fffffff;
            int jb = ib + (ib >= j ? 1 : 0);
            int vb = (ib < 15) ? i * 256 + jb * 16 + k : 0x7fffffff;
            int kc = ic + (ic >= k ? 1 : 0);
            int vc = (ic < 15) ? i * 256 + j * 16 + kc : 0x7fffffff;
            int v;
            if (va < vb && va < vc)      { v = va; ++ia; }
            else if (vb < vc)            { v = vb; ++ib; }
            else                         { v = vc; ++ic; }
            nbr[n * EE + e] = v;
        }
    }
    for (int idx = gtid; idx < NN * DS; idx += 512 * 256) {
        int n = idx >> 6, s = idx & 63;
        int i = n >> 8, j = (n >> 4) & 15, k = n & 15;
        float p0 = i * (1.f / 15.f) - 0.5f;
        float p1 = j * (1.f / 15.f) - 0.5f;
        float p2 = k * (1.f / 15.f) - 0.5f;
        p_theta[idx] = p0 * gt_w[s * 3] + p1 * gt_w[s * 3 + 1] + p2 * gt_w[s * 3 + 2] + gt_b[s];
        p_phi[idx]   = p0 * gp_w[s * 3] + p1 * gp_w[s * 3 + 1] + p2 * gp_w[s * 3 + 2] + gp_b[s];
    }
    {   // h[b][n][c] = x[b][c][n], one 64n x 32c tile per block
        int n0 = (bid & 63) * 64, c0 = ((bid >> 6) & 3) * 32, b = bid >> 8;
        for (int q = t; q < 2048; q += 256) {
            int cl = q >> 6, nl = q & 63;
            xs[cl * 65 + nl] = x[(size_t)(b * CC + c0 + cl) * NN + n0 + nl];
        }
        __syncthreads();
        for (int q = t; q < 2048; q += 256) {
            int nl = q >> 5, cl = q & 31;
            h[(size_t)(b * NN + n0 + nl) * CC + c0 + cl] = xs[cl * 65 + nl];
        }
    }
}

// ===========================================================================
// proj: [8192x128]x[128x192]^T GEMM (blocks 0..383, 64x64 tiles, XOR-swizzled
// LDS, 4x4 register blocking). Blocks >=384 (round-0 launch only) compute the
// one-time geo f_p raw dots + colnorm_p atomics.
__global__ __launch_bounds__(256) void k_proj(
    const float* __restrict__ h,
    const float* __restrict__ th_w, const float* __restrict__ th_b,
    const float* __restrict__ ph_w, const float* __restrict__ ph_b,
    const float* __restrict__ G_w,  const float* __restrict__ G_b,
    float* __restrict__ T, float* __restrict__ P, float* __restrict__ Gx,
    const int* __restrict__ nbr,
    const float* __restrict__ p_theta, const float* __restrict__ p_phi,
    float* __restrict__ f_p, float* __restrict__ colnorm_p)
{
    __shared__ __align__(16) float smf[16384];   // 64 KB
    const int t = threadIdx.x;
    if (blockIdx.x < 384) {
        int row0 = (blockIdx.x & 127) * 64;
        int cgp = blockIdx.x >> 7;
        const float* w    = cgp == 0 ? th_w : cgp == 1 ? ph_w : G_w;
        const float* bias = cgp == 0 ? th_b : cgp == 1 ? ph_b : G_b;
        float* o          = cgp == 0 ? T    : cgp == 1 ? P    : Gx;
        float4* hs4 = (float4*)smf;
        float4* ws4 = (float4*)smf + 2048;
        const float4* h4 = (const float4*)h;
        const float4* w4 = (const float4*)w;
        for (int q = t; q < 2048; q += 256) {
            int row = q >> 5, kc = q & 31;
            hs4[row * 32 + (kc ^ (row & 31))] = h4[(size_t)(row0 + row) * 32 + kc];
            ws4[row * 32 + (kc ^ (row & 31))] = w4[q];
        }
        __syncthreads();
        const int rt = t >> 4, m = t & 15;
        float acc[4][4] = {};
        for (int kc = 0; kc < 32; ++kc) {
            float4 a[4], wv[4];
#pragma unroll
            for (int rr = 0; rr < 4; ++rr) {
                int rw_ = rt * 4 + rr;
                a[rr] = hs4[rw_ * 32 + (kc ^ (rw_ & 31))];
            }
#pragma unroll
            for (int i = 0; i < 4; ++i) {
                int c = m + 16 * i;
                wv[i] = ws4[c * 32 + (kc ^ (c & 31))];
            }
#pragma unroll
            for (int rr = 0; rr < 4; ++rr)
#pragma unroll
                for (int i = 0; i < 4; ++i)
                    acc[rr][i] += a[rr].x * wv[i].x + a[rr].y * wv[i].y
                                + a[rr].z * wv[i].z + a[rr].w * wv[i].w;
        }
#pragma unroll
        for (int i = 0; i < 4; ++i) {
            float bv = bias[m + 16 * i];
#pragma unroll
            for (int rr = 0; rr < 4; ++rr)
                o[(size_t)(row0 + rt * 4 + rr) * DS + m + 16 * i] = acc[rr][i] + bv;
        }
    } else {
        // geo f_p: tile = blockIdx.x - 384 (b implicit 0, batch-identical)
        const int tile = blockIdx.x - 384;
        float4* ts4 = (float4*)smf;          // [16][17] f4  (dw 0..1087)
        int*    nbs = (int*)(smf + 1088);    // 736 ints
        float*  fvs = smf + 1824;            // 736 floats
        {
            int node = t >> 4, kc = t & 15;
            ts4[node * 17 + kc] =
                ((const float4*)p_theta)[(size_t)(tile * 16 + node) * 16 + kc];
        }
        for (int i2 = t; i2 < 16 * EE; i2 += 256) nbs[i2] = nbr[tile * 16 * EE + i2];
        __syncthreads();
        const int g = t >> 4, kc = t & 15;
        const float4 av = ts4[g * 17 + kc];
        const float4* P4 = (const float4*)p_phi;
        for (int e = 0; e < EE; ++e) {
            int m = nbs[g * EE + e];
            float4 p = P4[(size_t)m * 16 + kc];
            float v = av.x * p.x + av.y * p.y + av.z * p.z + av.w * p.w;
            v += __shfl_xor(v, 1);
            v += __shfl_xor(v, 2);
            v += __shfl_xor(v, 4);
            v += __shfl_xor(v, 8);
            if (kc == 0) {
                f_p[(size_t)(tile * 16 + g) * EE + e] = v;
                fvs[e * 16 + g] = v;
            }
        }
        __syncthreads();
        if (t < EE) {
            float s = 0.f;
#pragma unroll
            for (int q = 0; q < 16; ++q) { float v = fvs[t * 16 + q]; s += v * v; }
            atomicAdd(colnorm_p + t * CPAD, s);
        }
    }
}

// ===========================================================================
// Fused f + attn. Phase 1: f dots into LDS + device-scope atomicAdd of sumsq
// partials (these land at the coherence point). Barrier: one RELEASE
// fetch_add per block + RELAXED polling (NO acquire -> no cache invalidation
// -> phase-1 cached gather data survives into phase 2; the only cross-block
// values, colnorm_f, are read with coherence-point RELAXED atomic loads).
// Phase 2: softmax + gather + r_w epilogue + residual.
__global__ __launch_bounds__(256, 2) void k_fattn(
    const int* __restrict__ nbr,
    const float* __restrict__ T, const float* __restrict__ P,
    const float* __restrict__ Gx, const float* __restrict__ f_p,
    const float* __restrict__ colnorm_p, float* __restrict__ colnorm_f,
    int* __restrict__ ctr,
    const float* __restrict__ r_w, const float* __restrict__ r_b,
    float* __restrict__ h)
{
    __shared__ __align__(16) float smf[10752];   // 43008 B
    float4* rws4 = (float4*)smf;                 // dw 0..8191 (rotation-swz)
    float4* ts4  = (float4*)(smf + 8192);        // [16][17] f4, dw 8192..9279
    float*  ys   = smf + 8192;                   // reuse as [16][68]
    int*    nbs  = (int*)(smf + 9280);           // 736 ints
    float*  fvs  = smf + 10016;                  // 736 floats

    const int t = threadIdx.x;
    const int u = blockIdx.x;                    // 0..511
    const int b = u >> 8, tile = u & 255, n0 = tile * 16;

    // ---- stage T rows, neighbor tile, r_w -----------------------------------
    {
        int node = t >> 4, kc = t & 15;
        ts4[node * 17 + kc] =
            ((const float4*)T)[(size_t)(b * NN + n0 + node) * 16 + kc];
    }
    for (int i2 = t; i2 < 16 * EE; i2 += 256) nbs[i2] = nbr[n0 * EE + i2];
    for (int i2 = t; i2 < 2048; i2 += 256) {
        int c = i2 >> 4, g4 = i2 & 15;
        rws4[c * 16 + ((g4 + c) & 15)] = ((const float4*)r_w)[i2];
    }
    __syncthreads();

    // ---- phase 1: f dots (kept in LDS, never written to global) -------------
    const int g = t >> 4, kc = t & 15;
    const float4 av = ts4[g * 17 + kc];
    const float4* P4 = (const float4*)P;
    for (int e = 0; e < EE; ++e) {
        int m = nbs[g * EE + e];
        float4 p = P4[((size_t)b * NN + m) * 16 + kc];
        float v = av.x * p.x + av.y * p.y + av.z * p.z + av.w * p.w;
        v += __shfl_xor(v, 1);
        v += __shfl_xor(v, 2);
        v += __shfl_xor(v, 4);
        v += __shfl_xor(v, 8);
        if (kc == 0) fvs[e * 16 + g] = v;
    }
    __syncthreads();
    if (t < EE) {
        float s = 0.f;
#pragma unroll
        for (int q = 0; q < 16; ++q) { float v = fvs[t * 16 + q]; s += v * v; }
        atomicAdd(colnorm_f + (b * EE + t) * CPAD, s);
    }
    __syncthreads();   // drains vmcnt: colnorm atomics complete before arrive

    // ---- lightweight global barrier: RELEASE arrive + RELAXED poll ----------
    if (t == 0) {
        __hip_atomic_fetch_add(ctr, 1, __ATOMIC_RELEASE, __HIP_MEMORY_SCOPE_AGENT);
        while (__hip_atomic_load(ctr, __ATOMIC_RELAXED, __HIP_MEMORY_SCOPE_AGENT)
               < BB * 256)
            __builtin_amdgcn_s_sleep(8);
    }
    __syncthreads();

    // ---- phase 2: softmax + gather + epilogue -------------------------------
    const int wv = t >> 6, l = t & 63;
    float nf_inv = 0.f, np_inv = 0.f;
    if (l < EE) {
        float cf = __hip_atomic_load(colnorm_f + (b * EE + l) * CPAD,
                                     __ATOMIC_RELAXED, __HIP_MEMORY_SCOPE_AGENT);
        float cp = colnorm_p[l * CPAD];
        nf_inv = 1.f / (1e-6f + sqrtf(cf));
        np_inv = 1.f / (1e-6f + sqrtf(cp));
    }
    const float* Gb = Gx + (size_t)b * NN * DS;
    for (int ii = 0; ii < 4; ++ii) {
        int nl = wv * 4 + ii;
        int n = n0 + nl;
        float fvv = -INFINITY; int nb = 0;
        if (l < EE) {
            float fpv = f_p[(size_t)n * EE + l] * np_inv;
            fpv = fpv > 0.f ? fpv : 0.f;
            fvv = fvs[l * 16 + nl] * nf_inv + fpv;
            nb = nbs[nl * EE + l];
        }
        float mx = fvv;
        for (int o = 32; o; o >>= 1) mx = fmaxf(mx, __shfl_down(mx, o));
        mx = __shfl(mx, 0);
        float ex = (l < EE) ? expf(fvv - mx) : 0.f;
        float sm = ex;
        for (int o = 32; o; o >>= 1) sm += __shfl_down(sm, o);
        sm = __shfl(sm, 0);
        float at = ex / sm;
        float y0 = 0.f, y1 = 0.f;
        for (int e = 0; e < EE; e += 2) {
            float a0 = __shfl(at, e);     int m0 = __shfl(nb, e);
            float a1 = __shfl(at, e + 1); int m1 = __shfl(nb, e + 1);
            y0 += a0 * Gb[(size_t)m0 * DS + l];
            y1 += a1 * Gb[(size_t)m1 * DS + l];
        }
        ys[nl * 68 + l] = y0 + y1;
    }
    __syncthreads();

    // epilogue: delta[16][128] = y[16][64] @ rw[128][64]^T, residual into h
    const int r0 = (t >> 5) * 2, cl = t & 31;
    float4* ys4 = (float4*)ys;                   // row stride 17 f4
    float acc[2][4] = {{0, 0, 0, 0}, {0, 0, 0, 0}};
    for (int g4 = 0; g4 < 16; ++g4) {
        float4 ya = ys4[r0 * 17 + g4];
        float4 yb = ys4[(r0 + 1) * 17 + g4];
#pragma unroll
        for (int cc = 0; cc < 4; ++cc) {
            int c = cl + 32 * cc;
            float4 w = rws4[c * 16 + ((g4 + c) & 15)];
            acc[0][cc] += ya.x * w.x + ya.y * w.y + ya.z * w.z + ya.w * w.w;
            acc[1][cc] += yb.x * w.x + yb.y * w.y + yb.z * w.z + yb.w * w.w;
        }
    }
#pragma unroll
    for (int rr = 0; rr < 2; ++rr) {
        size_t bn = (size_t)b * NN + n0 + r0 + rr;
#pragma unroll
        for (int cc = 0; cc < 4; ++cc) {
            int c = cl + 32 * cc;
            h[bn * CC + c] += acc[rr][cc] + r_b[c];
        }
    }
}

// ===========================================================================
// out[b][c][n] = h[b][n][c]
__global__ __launch_bounds__(256) void k_out(const float* __restrict__ h,
                                             float* __restrict__ out) {
    __shared__ float hs_[64][33];
    const int t = threadIdx.x;
    const int n0 = blockIdx.x * 64, c0 = blockIdx.y * 32, b = blockIdx.z;
    for (int q = t; q < 2048; q += 256) {
        int nl = q >> 5, cl = q & 31;
        hs_[nl][cl] = h[(size_t)(b * NN + n0 + nl) * CC + c0 + cl];
    }
    __syncthreads();
    for (int q = t; q < 2048; q += 256) {
        int cl = q >> 6, nl = q & 63;
        out[(size_t)(b * CC + c0 + cl) * NN + n0 + nl] = hs_[nl][cl];
    }
}

// ===========================================================================
extern "C" void kernel_launch(void* const* d_in, const int* in_sizes, int n_in,
                              void* d_out, int out_size, void* d_ws, size_t ws_size,
                              hipStream_t stream) {
    const float* x    = (const float*)d_in[0];
    const float* G_w  = (const float*)d_in[1];
    const float* G_b  = (const float*)d_in[2];
    const float* th_w = (const float*)d_in[3];
    const float* th_b = (const float*)d_in[4];
    const float* ph_w = (const float*)d_in[5];
    const float* ph_b = (const float*)d_in[6];
    const float* r_w  = (const float*)d_in[7];
    const float* r_b  = (const float*)d_in[8];
    const float* gt_w = (const float*)d_in[9];
    const float* gt_b = (const float*)d_in[10];
    const float* gp_w = (const float*)d_in[11];
    const float* gp_b = (const float*)d_in[12];
    float* out = (float*)d_out;

    // Workspace layout (byte offsets, 256-aligned)
    char* ws = (char*)d_ws;
    size_t off = 0;
    auto alloc = [&](size_t bytes) {
        char* p = ws + off;
        off = (off + bytes + 255) & ~size_t(255);
        return p;
    };
    int*   nbr       = (int*)  alloc((size_t)NN * EE * sizeof(int));
    float* p_theta   = (float*)alloc((size_t)NN * DS * sizeof(float));
    float* p_phi     = (float*)alloc((size_t)NN * DS * sizeof(float));
    float* f_p       = (float*)alloc((size_t)NN * EE * sizeof(float));
    float* colnorm_p = (float*)alloc((size_t)EE * CPAD * sizeof(float));
    float* colnorm_f = (float*)alloc((size_t)3 * BB * EE * CPAD * sizeof(float));
    int*   ctr       = (int*)  alloc(4 * sizeof(int));
    float* h         = (float*)alloc((size_t)BB * NN * CC * sizeof(float));
    float* T         = (float*)alloc((size_t)BB * NN * DS * sizeof(float));
    float* P         = (float*)alloc((size_t)BB * NN * DS * sizeof(float));
    float* Gx        = (float*)alloc((size_t)BB * NN * DS * sizeof(float));
    (void)ws_size; (void)in_sizes; (void)n_in; (void)out_size;

    k_setup<<<512, 256, 0, stream>>>(x, gt_w, gt_b, gp_w, gp_b, nbr,
                                     p_theta, p_phi, colnorm_p, colnorm_f, ctr, h);
    for (int r = 0; r < 3; ++r) {
        // round 0 carries the one-time geo f_p blocks (384..639)
        int nblk = (r == 0) ? 640 : 384;
        k_proj<<<nblk, 256, 0, stream>>>(h, th_w, th_b, ph_w, ph_b, G_w, G_b,
                                         T, P, Gx, nbr, p_theta, p_phi,
                                         f_p, colnorm_p);
        k_fattn<<<512, 256, 0, stream>>>(nbr, T, P, Gx, f_p, colnorm_p,
                                         colnorm_f + (size_t)r * BB * EE * CPAD,
                                         ctr + r, r_w, r_b, h);
    }
    k_out<<<dim3(64, 4, 2), 256, 0, stream>>>(h, out);
}

// Round 7
// 210.719 us; speedup vs baseline: 2.9375x; 1.4183x over previous
//
#include <hip/hip_runtime.h>
#include <math.h>

// Problem constants
#define BB 2
#define CC 128
#define NN 4096            // D*H*W = 16*16*16
#define EE 46              // 16 + 15 + 15 neighbors
#define EH 23              // EE/2 per e-half block
#define DS 64              // DSIM = PSIM = GDIM = 64
#define CPAD 16            // dwords per colnorm counter (one 64B line each)

// ===========================================================================
// Setup: zero colnorms, neighbor table, geo projections, h transpose.
// grid 512 x 256.
__global__ __launch_bounds__(256) void k_setup(
    const float* __restrict__ x,
    const float* __restrict__ gt_w, const float* __restrict__ gt_b,
    const float* __restrict__ gp_w, const float* __restrict__ gp_b,
    int* __restrict__ nbr, float* __restrict__ p_theta, float* __restrict__ p_phi,
    float* __restrict__ colnorm_p, float* __restrict__ colnorm_f,
    float* __restrict__ h)
{
    __shared__ float xs[32 * 65];
    const int t = threadIdx.x, bid = blockIdx.x;
    const int gtid = bid * 256 + t;

    if (gtid < EE * CPAD) colnorm_p[gtid] = 0.f;
    if (gtid < 3 * BB * EE * CPAD) colnorm_f[gtid] = 0.f;

    if (gtid < NN) {   // sorted 3-way merge of axis neighbor lists
        int n = gtid;
        int i = n >> 8, j = (n >> 4) & 15, k = n & 15;
        int ia = 0, ib = 0, ic = 0;
        for (int e = 0; e < EE; ++e) {
            int va = (ia < 16) ? ia * 256 + j * 16 + k : 0x7fffffff;
            int jb = ib + (ib >= j ? 1 : 0);
            int vb = (ib < 15) ? i * 256 + jb * 16 + k : 0x7fffffff;
            int kc = ic + (ic >= k ? 1 : 0);
            int vc = (ic < 15) ? i * 256 + j * 16 + kc : 0x7fffffff;
            int v;
            if (va < vb && va < vc)      { v = va; ++ia; }
            else if (vb < vc)            { v = vb; ++ib; }
            else                         { v = vc; ++ic; }
            nbr[n * EE + e] = v;
        }
    }
    for (int idx = gtid; idx < NN * DS; idx += 512 * 256) {
        int n = idx >> 6, s = idx & 63;
        int i = n >> 8, j = (n >> 4) & 15, k = n & 15;
        float p0 = i * (1.f / 15.f) - 0.5f;
        float p1 = j * (1.f / 15.f) - 0.5f;
        float p2 = k * (1.f / 15.f) - 0.5f;
        p_theta[idx] = p0 * gt_w[s * 3] + p1 * gt_w[s * 3 + 1] + p2 * gt_w[s * 3 + 2] + gt_b[s];
        p_phi[idx]   = p0 * gp_w[s * 3] + p1 * gp_w[s * 3 + 1] + p2 * gp_w[s * 3 + 2] + gp_b[s];
    }
    {   // h[b][n][c] = x[b][c][n], one 64n x 32c tile per block
        int n0 = (bid & 63) * 64, c0 = ((bid >> 6) & 3) * 32, b = bid >> 8;
        for (int q = t; q < 2048; q += 256) {
            int cl = q >> 6, nl = q & 63;
            xs[cl * 65 + nl] = x[(size_t)(b * CC + c0 + cl) * NN + n0 + nl];
        }
        __syncthreads();
        for (int q = t; q < 2048; q += 256) {
            int nl = q >> 5, cl = q & 31;
            h[(size_t)(b * NN + n0 + nl) * CC + c0 + cl] = xs[cl * 65 + nl];
        }
    }
}

// ===========================================================================
// proj: [8192x128]x[128x192]^T GEMM (blocks 0..383, 64x64 tiles, XOR-swizzled
// LDS, 4x4 register blocking). Blocks >=384 (round-0 launch only) compute the
// one-time geo f_p raw dots + colnorm_p atomics.
__global__ __launch_bounds__(256) void k_proj(
    const float* __restrict__ h,
    const float* __restrict__ th_w, const float* __restrict__ th_b,
    const float* __restrict__ ph_w, const float* __restrict__ ph_b,
    const float* __restrict__ G_w,  const float* __restrict__ G_b,
    float* __restrict__ T, float* __restrict__ P, float* __restrict__ Gx,
    const int* __restrict__ nbr,
    const float* __restrict__ p_theta, const float* __restrict__ p_phi,
    float* __restrict__ f_p, float* __restrict__ colnorm_p)
{
    __shared__ __align__(16) float smf[16384];   // 64 KB
    const int t = threadIdx.x;
    if (blockIdx.x < 384) {
        int row0 = (blockIdx.x & 127) * 64;
        int cgp = blockIdx.x >> 7;
        const float* w    = cgp == 0 ? th_w : cgp == 1 ? ph_w : G_w;
        const float* bias = cgp == 0 ? th_b : cgp == 1 ? ph_b : G_b;
        float* o          = cgp == 0 ? T    : cgp == 1 ? P    : Gx;
        float4* hs4 = (float4*)smf;
        float4* ws4 = (float4*)smf + 2048;
        const float4* h4 = (const float4*)h;
        const float4* w4 = (const float4*)w;
        for (int q = t; q < 2048; q += 256) {
            int row = q >> 5, kc = q & 31;
            hs4[row * 32 + (kc ^ (row & 31))] = h4[(size_t)(row0 + row) * 32 + kc];
            ws4[row * 32 + (kc ^ (row & 31))] = w4[q];
        }
        __syncthreads();
        const int rt = t >> 4, m = t & 15;
        float acc[4][4] = {};
        for (int kc = 0; kc < 32; ++kc) {
            float4 a[4], wv[4];
#pragma unroll
            for (int rr = 0; rr < 4; ++rr) {
                int rw_ = rt * 4 + rr;
                a[rr] = hs4[rw_ * 32 + (kc ^ (rw_ & 31))];
            }
#pragma unroll
            for (int i = 0; i < 4; ++i) {
                int c = m + 16 * i;
                wv[i] = ws4[c * 32 + (kc ^ (c & 31))];
            }
#pragma unroll
            for (int rr = 0; rr < 4; ++rr)
#pragma unroll
                for (int i = 0; i < 4; ++i)
                    acc[rr][i] += a[rr].x * wv[i].x + a[rr].y * wv[i].y
                                + a[rr].z * wv[i].z + a[rr].w * wv[i].w;
        }
#pragma unroll
        for (int i = 0; i < 4; ++i) {
            float bv = bias[m + 16 * i];
#pragma unroll
            for (int rr = 0; rr < 4; ++rr)
                o[(size_t)(row0 + rt * 4 + rr) * DS + m + 16 * i] = acc[rr][i] + bv;
        }
    } else {
        // geo f_p: tile = blockIdx.x - 384 (b implicit 0, batch-identical)
        const int tile = blockIdx.x - 384;
        float4* ts4 = (float4*)smf;          // [16][17] f4  (dw 0..1087)
        int*    nbs = (int*)(smf + 1088);    // 736 ints
        float*  fvs = smf + 1824;            // 736 floats
        {
            int node = t >> 4, kc = t & 15;
            ts4[node * 17 + kc] =
                ((const float4*)p_theta)[(size_t)(tile * 16 + node) * 16 + kc];
        }
        for (int i2 = t; i2 < 16 * EE; i2 += 256) nbs[i2] = nbr[tile * 16 * EE + i2];
        __syncthreads();
        const int g = t >> 4, kc = t & 15;
        const float4 av = ts4[g * 17 + kc];
        const float4* P4 = (const float4*)p_phi;
        for (int e = 0; e < EE; ++e) {
            int m = nbs[g * EE + e];
            float4 p = P4[(size_t)m * 16 + kc];
            float v = av.x * p.x + av.y * p.y + av.z * p.z + av.w * p.w;
            v += __shfl_xor(v, 1);
            v += __shfl_xor(v, 2);
            v += __shfl_xor(v, 4);
            v += __shfl_xor(v, 8);
            if (kc == 0) {
                f_p[(size_t)(tile * 16 + g) * EE + e] = v;
                fvs[e * 16 + g] = v;
            }
        }
        __syncthreads();
        if (t < EE) {
            float s = 0.f;
#pragma unroll
            for (int q = 0; q < 16; ++q) { float v = fvs[t * 16 + q]; s += v * v; }
            atomicAdd(colnorm_p + t * CPAD, s);
        }
    }
}

// ===========================================================================
// k_f: f[b][n][e] = dot64(T[b,n], P[b,nbr[n,e]]) for one (tile, e-half, b).
// grid (256, 2, BB) = 1024 blocks, ~8.8 KB LDS -> 4 blocks/CU, 16 waves/CU.
// 16 groups of 16 lanes: group = node, lane = float4 chunk (coalesced 256 B
// row per gather). Writes raw f + per-(b,e) sumsq atomics.
__global__ __launch_bounds__(256) void k_f(
    const int* __restrict__ nbr,
    const float* __restrict__ T, const float* __restrict__ P,
    float* __restrict__ f, float* __restrict__ colnorm)
{
    __shared__ __align__(16) float smf[2560];
    float4* ts4 = (float4*)smf;            // [16][17] f4  (dw 0..1087)
    int*    nbs = (int*)(smf + 1088);      // 736 ints
    float*  fvs = smf + 1824;              // [EH][16] floats

    const int t = threadIdx.x;
    const int tile = blockIdx.x, half = blockIdx.y, b = blockIdx.z;
    const int n0 = tile * 16, e0 = half * EH;
    {
        int node = t >> 4, kc = t & 15;
        ts4[node * 17 + kc] =
            ((const float4*)T)[(size_t)(b * NN + n0 + node) * 16 + kc];
    }
    for (int i2 = t; i2 < 16 * EE; i2 += 256) nbs[i2] = nbr[n0 * EE + i2];
    __syncthreads();

    const int g = t >> 4, kc = t & 15;
    const float4 av = ts4[g * 17 + kc];
    const float4* P4 = (const float4*)P;
    for (int ee = 0; ee < EH; ++ee) {
        int m = nbs[g * EE + e0 + ee];
        float4 p = P4[((size_t)b * NN + m) * 16 + kc];
        float v = av.x * p.x + av.y * p.y + av.z * p.z + av.w * p.w;
        v += __shfl_xor(v, 1);
        v += __shfl_xor(v, 2);
        v += __shfl_xor(v, 4);
        v += __shfl_xor(v, 8);
        if (kc == 0) fvs[ee * 16 + g] = v;
    }
    __syncthreads();

    for (int i = t; i < 16 * EH; i += 256) {
        int nl = i / EH, ee = i - nl * EH;
        f[(size_t)(b * NN + n0 + nl) * EE + e0 + ee] = fvs[ee * 16 + nl];
    }
    if (t < EH) {
        float s = 0.f;
#pragma unroll
        for (int q = 0; q < 16; ++q) { float v = fvs[t * 16 + q]; s += v * v; }
        atomicAdd(colnorm + (b * EE + e0 + t) * CPAD, s);
    }
}

// ===========================================================================
// k_attn: per (b, 16-node tile): normalize f, add relu'd normalized f_p,
// softmax over 46, gather Gx, r_w epilogue (direct L1-resident float4 reads),
// residual. LAST=1: write transposed out directly (full 64 B lines per block)
// and skip the dead h write.  ~7.3 KB LDS.
template <int LAST>
__global__ __launch_bounds__(256) void k_attn(
    const int* __restrict__ nbr,
    const float* __restrict__ f, const float* __restrict__ f_p,
    const float* __restrict__ colnorm_p, const float* __restrict__ colnorm_f,
    const float* __restrict__ Gx,
    const float* __restrict__ r_w, const float* __restrict__ r_b,
    float* __restrict__ h, float* __restrict__ out)
{
    __shared__ __align__(16) float smf[1824];
    float* ys  = smf;                      // [16][68] dwords (dw 0..1087)
    int*   nbs = (int*)(smf + 1088);       // 736 ints

    const int t = threadIdx.x;
    const int u = blockIdx.x;              // 0..511
    const int b = u >> 8, tile = u & 255, n0 = tile * 16;

    for (int i2 = t; i2 < 16 * EE; i2 += 256) nbs[i2] = nbr[n0 * EE + i2];
    __syncthreads();

    const int wv = t >> 6, l = t & 63;
    float nf_inv = 0.f, np_inv = 0.f;
    if (l < EE) {
        nf_inv = 1.f / (1e-6f + sqrtf(colnorm_f[(b * EE + l) * CPAD]));
        np_inv = 1.f / (1e-6f + sqrtf(colnorm_p[l * CPAD]));
    }
    const float* Gb = Gx + (size_t)b * NN * DS;
    for (int ii = 0; ii < 4; ++ii) {
        int nl = wv * 4 + ii;
        int n = n0 + nl;
        float fvv = -INFINITY; int nb = 0;
        if (l < EE) {
            float fpv = f_p[(size_t)n * EE + l] * np_inv;
            fpv = fpv > 0.f ? fpv : 0.f;
            fvv = f[(size_t)(b * NN + n) * EE + l] * nf_inv + fpv;
            nb = nbs[nl * EE + l];
        }
        float mx = fvv;
        for (int o = 32; o; o >>= 1) mx = fmaxf(mx, __shfl_down(mx, o));
        mx = __shfl(mx, 0);
        float ex = (l < EE) ? expf(fvv - mx) : 0.f;
        float sm = ex;
        for (int o = 32; o; o >>= 1) sm += __shfl_down(sm, o);
        sm = __shfl(sm, 0);
        float at = ex / sm;
        float y0 = 0.f, y1 = 0.f;
        for (int e = 0; e < EE; e += 2) {
            float a0 = __shfl(at, e);     int m0 = __shfl(nb, e);
            float a1 = __shfl(at, e + 1); int m1 = __shfl(nb, e + 1);
            y0 += a0 * Gb[(size_t)m0 * DS + l];
            y1 += a1 * Gb[(size_t)m1 * DS + l];
        }
        ys[nl * 68 + l] = y0 + y1;
    }
    __syncthreads();

    // epilogue: delta[16][128] = y[16][64] @ rw[128][64]^T, direct rw reads
    const int r0 = (t >> 5) * 2, cl = t & 31;
    const float4* rw4 = (const float4*)r_w;
    float4* ys4 = (float4*)ys;             // row stride 17 f4
    float acc[2][4] = {{0, 0, 0, 0}, {0, 0, 0, 0}};
    for (int g4 = 0; g4 < 16; ++g4) {
        float4 ya = ys4[r0 * 17 + g4];
        float4 yb = ys4[(r0 + 1) * 17 + g4];
#pragma unroll
        for (int cc = 0; cc < 4; ++cc) {
            int c = cl + 32 * cc;
            float4 w = rw4[c * 16 + g4];
            acc[0][cc] += ya.x * w.x + ya.y * w.y + ya.z * w.z + ya.w * w.w;
            acc[1][cc] += yb.x * w.x + yb.y * w.y + yb.z * w.z + yb.w * w.w;
        }
    }
#pragma unroll
    for (int rr = 0; rr < 2; ++rr) {
        int n = n0 + r0 + rr;
        size_t bn = (size_t)b * NN + n;
#pragma unroll
        for (int cc = 0; cc < 4; ++cc) {
            int c = cl + 32 * cc;
            float val = h[bn * CC + c] + acc[rr][cc] + r_b[c];
            if (LAST) out[(size_t)(b * CC + c) * NN + n] = val;
            else      h[bn * CC + c] = val;
        }
    }
}

// ===========================================================================
extern "C" void kernel_launch(void* const* d_in, const int* in_sizes, int n_in,
                              void* d_out, int out_size, void* d_ws, size_t ws_size,
                              hipStream_t stream) {
    const float* x    = (const float*)d_in[0];
    const float* G_w  = (const float*)d_in[1];
    const float* G_b  = (const float*)d_in[2];
    const float* th_w = (const float*)d_in[3];
    const float* th_b = (const float*)d_in[4];
    const float* ph_w = (const float*)d_in[5];
    const float* ph_b = (const float*)d_in[6];
    const float* r_w  = (const float*)d_in[7];
    const float* r_b  = (const float*)d_in[8];
    const float* gt_w = (const float*)d_in[9];
    const float* gt_b = (const float*)d_in[10];
    const float* gp_w = (const float*)d_in[11];
    const float* gp_b = (const float*)d_in[12];
    float* out = (float*)d_out;

    // Workspace layout (byte offsets, 256-aligned)
    char* ws = (char*)d_ws;
    size_t off = 0;
    auto alloc = [&](size_t bytes) {
        char* p = ws + off;
        off = (off + bytes + 255) & ~size_t(255);
        return p;
    };
    int*   nbr       = (int*)  alloc((size_t)NN * EE * sizeof(int));
    float* p_theta   = (float*)alloc((size_t)NN * DS * sizeof(float));
    float* p_phi     = (float*)alloc((size_t)NN * DS * sizeof(float));
    float* f_p       = (float*)alloc((size_t)NN * EE * sizeof(float));
    float* colnorm_p = (float*)alloc((size_t)EE * CPAD * sizeof(float));
    float* colnorm_f = (float*)alloc((size_t)3 * BB * EE * CPAD * sizeof(float));
    float* h         = (float*)alloc((size_t)BB * NN * CC * sizeof(float));
    float* T         = (float*)alloc((size_t)BB * NN * DS * sizeof(float));
    float* P         = (float*)alloc((size_t)BB * NN * DS * sizeof(float));
    float* Gx        = (float*)alloc((size_t)BB * NN * DS * sizeof(float));
    float* f         = (float*)alloc((size_t)BB * NN * EE * sizeof(float));
    (void)ws_size; (void)in_sizes; (void)n_in; (void)out_size;

    k_setup<<<512, 256, 0, stream>>>(x, gt_w, gt_b, gp_w, gp_b, nbr,
                                     p_theta, p_phi, colnorm_p, colnorm_f, h);
    for (int r = 0; r < 3; ++r) {
        float* cn = colnorm_f + (size_t)r * BB * EE * CPAD;
        // round 0 carries the one-time geo f_p blocks (384..639)
        int nblk = (r == 0) ? 640 : 384;
        k_proj<<<nblk, 256, 0, stream>>>(h, th_w, th_b, ph_w, ph_b, G_w, G_b,
                                         T, P, Gx, nbr, p_theta, p_phi,
                                         f_p, colnorm_p);
        k_f<<<dim3(256, 2, BB), 256, 0, stream>>>(nbr, T, P, f, cn);
        if (r < 2)
            k_attn<0><<<512, 256, 0, stream>>>(nbr, f, f_p, colnorm_p, cn, Gx,
                                               r_w, r_b, h, out);
        else
            k_attn<1><<<512, 256, 0, stream>>>(nbr, f, f_p, colnorm_p, cn, Gx,
                                               r_w, r_b, h, out);
    }
}